// Round 1
// 305.675 us; speedup vs baseline: 1.0295x; 1.0295x over previous
//
#include <hip/hip_runtime.h>
#include <hip/hip_bf16.h>

// LSTM: I=32, H=64, O=8, B=4096, T=256, fused single kernel.
// Round 7: BR=16, full-M MFMA (no mirror rows). grid=256, 1 block/CU.
//  - Each wave owns ONE 16-col hidden slice (jw = wave*16+nlow) x all 4 gates:
//    4 gate accumulators per lane are f32x4 D fragments whose rows
//    (lane>>4)*4 .. +3 are REAL batch rows -> cell update consumes acc[g]
//    directly. No mirror duplicates, no extraction.
//  - Total MFMA per step halves vs round 6 (M=16 fully used); barriers and
//    post-barrier LDS h-read latency events per row-step halve too.
//  - 4 waves/CU (1/SIMD): latency hidden by in-wave ILP (4 independent gate
//    chains, 4 packed cells, x-repack filler in the lgkm shadow).
//  - Activations: Pade rationals on f32x4 (packed f32 math), clamps via
//    v_med3_f32. h bf16 in LDS, double-buffered, ONE __syncthreads per step.

#define T_LEN 256
#define I_SZ  32
#define H_SZ  64
#define O_SZ  8
#define BR    16
#define HS    72   // h row stride in shorts (144 B: b128 reads uniform 8/slot)

typedef __attribute__((ext_vector_type(8))) short short8;
typedef __attribute__((ext_vector_type(4))) float f32x4;

static __device__ __forceinline__ unsigned fbits(float f) {
    union { float f; unsigned u; } v; v.f = f; return v.u;
}
// two floats -> packed bf16x2 (truncation): elem0 = lo, elem1 = hi
static __device__ __forceinline__ unsigned pk2t(float lo, float hi) {
    return __builtin_amdgcn_perm(fbits(hi), fbits(lo), 0x07060302u);
}
static __device__ __forceinline__ short f2bf_rne(float f) {   // init-time only
    union { __hip_bfloat16 b; short s; } u;
    u.b = __float2bfloat16(f);
    return u.s;
}
static __device__ __forceinline__ f32x4 rcp4(f32x4 d) {
    f32x4 r;
    r.x = __builtin_amdgcn_rcpf(d.x);
    r.y = __builtin_amdgcn_rcpf(d.y);
    r.z = __builtin_amdgcn_rcpf(d.z);
    r.w = __builtin_amdgcn_rcpf(d.w);
    return r;
}
static __device__ __forceinline__ f32x4 fma4(f32x4 a, f32x4 b, f32x4 c) {
    return __builtin_elementwise_fma(a, b, c);
}
static __device__ __forceinline__ f32x4 clamp4(f32x4 x, float lo, float hi) {
    f32x4 r;
    r.x = __builtin_amdgcn_fmed3f(x.x, lo, hi);
    r.y = __builtin_amdgcn_fmed3f(x.y, lo, hi);
    r.z = __builtin_amdgcn_fmed3f(x.z, lo, hi);
    r.w = __builtin_amdgcn_fmed3f(x.w, lo, hi);
    return r;
}
// tanh Pade[5/4], clamped. |err| <~ 1.1e-3, den >= 945.
static __device__ __forceinline__ f32x4 tanh4(f32x4 x) {
    f32x4 x2 = x * x;
    f32x4 n  = fma4(x2 + 105.0f, x2, (f32x4)(945.0f));
    f32x4 d  = fma4(fma4((f32x4)(15.0f), x2, (f32x4)(420.0f)), x2, (f32x4)(945.0f));
    f32x4 r  = (x * n) * rcp4(d);
    return clamp4(r, -1.0f, 1.0f);
}
// sigmoid = 0.5 + 0.5*tanh(x/2) via folded Pade. |err| <~ 5.5e-4.
static __device__ __forceinline__ f32x4 sig4(f32x4 x) {
    f32x4 x2 = x * x;
    f32x4 n  = fma4(x2 + 420.0f, x2, (f32x4)(15120.0f));
    f32x4 d  = fma4(fma4((f32x4)(60.0f), x2, (f32x4)(6720.0f)), x2, (f32x4)(60480.0f));
    f32x4 r  = fma4(x * n, rcp4(d), (f32x4)(0.5f));
    return clamp4(r, 0.0f, 1.0f);
}

__global__ __launch_bounds__(256, 1)
void lstm_fused_kernel(const float* __restrict__ x,
                       const float* __restrict__ W_ih,
                       const float* __restrict__ W_hh,
                       const float* __restrict__ b_ih,
                       const float* __restrict__ b_hh,
                       const float* __restrict__ W_fc,
                       const float* __restrict__ b_fc,
                       float* __restrict__ out)
{
    __shared__ short hbuf[2][BR][HS];   // h double buffer, bf16, 16 real rows
    __shared__ float Hf[BR][64];

    const int tid   = threadIdx.x;
    const int wave  = tid >> 6;
    const int lane  = tid & 63;
    const int quad  = lane >> 4;
    const int nlow  = lane & 15;
    const int jw    = wave * 16 + nlow;  // hidden col this lane's tiles own
    const int rbase = quad * 4;          // D rows this lane owns (real rows)
    const int b0    = blockIdx.x * BR;

    // ---- B fragments (weights) once into registers: 4 gates x 3 k-tiles.
    short8 bfrag[4][3];
    f32x4  biasf[4];
    for (int g = 0; g < 4; ++g) {
        const int col = g * 64 + jw;
        {
            const float* wr = W_ih + col * I_SZ + quad * 8;
            short8 f;
            #pragma unroll
            for (int e = 0; e < 8; ++e) f[e] = f2bf_rne(wr[e]);
            bfrag[g][0] = f;
        }
        #pragma unroll
        for (int kt = 1; kt < 3; ++kt) {
            const float* wr = W_hh + col * H_SZ + (kt - 1) * 32 + quad * 8;
            short8 f;
            #pragma unroll
            for (int e = 0; e < 8; ++e) f[e] = f2bf_rne(wr[e]);
            bfrag[g][kt] = f;
        }
        const float bg = b_ih[col] + b_hh[col];
        biasf[g] = (f32x4){bg, bg, bg, bg};
    }

    // ---- zero h buffers (h0 = 0)
    for (int q = tid; q < 2 * BR * HS; q += 256) ((short*)hbuf)[q] = (short)0;

    // ---- x machinery: lane owns x[b0+nlow][t][quad*8 .. +7] (A row = nlow).
    const float* xb = x + ((size_t)(b0 + nlow) * T_LEN) * I_SZ + quad * 8;

    float4 nx[16];                        // next-chunk fp32 (8 steps x 8 floats)
    short8 sc[8];                         // current-chunk bf16 fragments
    #pragma unroll
    for (int s = 0; s < 8; ++s) {
        nx[2*s]   = *(const float4*)(xb + s * I_SZ);
        nx[2*s+1] = *(const float4*)(xb + s * I_SZ + 4);
    }
    #pragma unroll
    for (int s = 0; s < 8; ++s) {
        union { uint4 u; short8 v; } w;
        w.u.x = pk2t(nx[2*s].x,   nx[2*s].y);
        w.u.y = pk2t(nx[2*s].z,   nx[2*s].w);
        w.u.z = pk2t(nx[2*s+1].x, nx[2*s+1].y);
        w.u.w = pk2t(nx[2*s+1].z, nx[2*s+1].w);
        sc[s] = w.v;
    }

    // LDS addresses: read A rows by nlow; write own 4 cell rows at col jw.
    const short* rb[2] = { &hbuf[0][nlow][quad * 8], &hbuf[1][nlow][quad * 8] };
    short*       wb[2] = { &hbuf[0][rbase][jw],      &hbuf[1][rbase][jw] };

    f32x4 cc = {0.f, 0.f, 0.f, 0.f};
    f32x4 hh = {0.f, 0.f, 0.f, 0.f};

    for (int ch = 0; ch < 32; ++ch) {
        #pragma unroll
        for (int tc = 0; tc < 8; ++tc) {
            const int t = ch * 8 + tc;

            __syncthreads();             // h_{t-1} (and at t=0 the zeroing) visible

            // h fragments: A[m = nlow][k = 32*kt + quad*8 + e]
            const short* hr = rb[t & 1];
            short8 a1 = *(const short8*)(hr);        // h cols  0..31
            short8 a2 = *(const short8*)(hr + 32);   // h cols 32..63

            // issue next chunk's global loads early in the chunk
            if (tc == 0 && ch + 1 < 32) {
                const float* nxt = xb + (t + 8) * I_SZ;
                #pragma unroll
                for (int s = 0; s < 8; ++s) {
                    nx[2*s]   = *(const float4*)(nxt + s * I_SZ);
                    nx[2*s+1] = *(const float4*)(nxt + s * I_SZ + 4);
                }
            }

            const short8 ax = sc[tc];

            // 4 independent gate chains; x-proj MFMA issues in the lgkm shadow.
            f32x4 acc[4];
            #pragma unroll
            for (int g = 0; g < 4; ++g) {
                f32x4 a = __builtin_amdgcn_mfma_f32_16x16x32_bf16(ax, bfrag[g][0], biasf[g], 0, 0, 0);
                a = __builtin_amdgcn_mfma_f32_16x16x32_bf16(a1, bfrag[g][1], a, 0, 0, 0);
                a = __builtin_amdgcn_mfma_f32_16x16x32_bf16(a2, bfrag[g][2], a, 0, 0, 0);
                acc[g] = a;
            }

            // convert next chunk once its loads landed (7 steps of cover);
            // independent ops = ILP filler for the MFMA/activation chains.
            if (tc == 7 && ch + 1 < 32) {
                #pragma unroll
                for (int s = 0; s < 8; ++s) {
                    union { uint4 u; short8 v; } w;
                    w.u.x = pk2t(nx[2*s].x,   nx[2*s].y);
                    w.u.y = pk2t(nx[2*s].z,   nx[2*s].w);
                    w.u.z = pk2t(nx[2*s+1].x, nx[2*s+1].y);
                    w.u.w = pk2t(nx[2*s+1].z, nx[2*s+1].w);
                    sc[s] = w.v;
                }
            }

            // ---- cell update: 4 real cells per lane, gates direct from acc.
            f32x4 iv = sig4(acc[0]);
            f32x4 fv = sig4(acc[1]);
            f32x4 gv = tanh4(acc[2]);
            f32x4 ov = sig4(acc[3]);
            cc = fma4(fv, cc, iv * gv);
            hh = ov * tanh4(cc);

            short* hw = wb[(t + 1) & 1];
            hw[0 * HS] = (short)((fbits(hh.x) + 0x8000u) >> 16);
            hw[1 * HS] = (short)((fbits(hh.y) + 0x8000u) >> 16);
            hw[2 * HS] = (short)((fbits(hh.z) + 0x8000u) >> 16);
            hw[3 * HS] = (short)((fbits(hh.w) + 0x8000u) >> 16);
        }
    }

    // ---- epilogue: out[b0+r][o] = h_T[r] . W_fc[o] + b_fc[o]  (fp32 h)
    Hf[rbase + 0][jw] = hh.x;
    Hf[rbase + 1][jw] = hh.y;
    Hf[rbase + 2][jw] = hh.z;
    Hf[rbase + 3][jw] = hh.w;
    __syncthreads();

    if (tid < BR * O_SZ) {               // 128 threads
        const int r = tid >> 3;
        const int o = tid & 7;
        const float* wf = W_fc + o * H_SZ;
        float acc = b_fc[o];
        #pragma unroll
        for (int jx = 0; jx < H_SZ; ++jx) acc += Hf[r][jx] * wf[jx];
        out[(size_t)(b0 + r) * O_SZ + o] = acc;
    }
}

extern "C" void kernel_launch(void* const* d_in, const int* in_sizes, int n_in,
                              void* d_out, int out_size, void* d_ws, size_t ws_size,
                              hipStream_t stream) {
    const float* x    = (const float*)d_in[0];
    const float* W_ih = (const float*)d_in[1];
    const float* W_hh = (const float*)d_in[2];
    const float* b_ih = (const float*)d_in[3];
    const float* b_hh = (const float*)d_in[4];
    const float* W_fc = (const float*)d_in[5];
    const float* b_fc = (const float*)d_in[6];
    float* out = (float*)d_out;

    const int B = 4096;
    lstm_fused_kernel<<<dim3(B / BR), dim3(256), 0, stream>>>(
        x, W_ih, W_hh, b_ih, b_hh, W_fc, b_fc, out);
}

// Round 4
// 288.031 us; speedup vs baseline: 1.0926x; 1.0613x over previous
//
#include <hip/hip_runtime.h>
#include <hip/hip_bf16.h>

// LSTM: I=32, H=64, O=8, B=4096, T=256, fused single kernel.
// Round 10: round-7 structure (BR=16 full-M MFMA, grid 256, 1 barrier/step)
// with activations moved to the HARDWARE TRANS PIPE via builtins only.
//  - Rounds 8/9 (v_pk_*_f32 inline asm) failed identically: MFMA->VALU RAW
//    hazard wait-states are NOT inserted by the compiler when the consumer
//    is inline asm (INLINEASM is not isVALU for the hazard recognizer).
//    Abandoned: builtins only, compiler owns all hazards.
//  - sigmoid(x) = rcp(1 + exp2(-x*log2e)) : 2 VALU + 2 TRANS per element.
//  - tanh(x)    = (e-1)*rcp(e+1), e = exp2(2x*log2e), x clamped +-10 : 5V+2T.
//    vs Pade ~10 VALU per element. TRANS (v_exp/v_rcp) runs on its own pipe,
//    overlapping VALU issue. Accuracy better than Pade (HW exp ~1ulp).
//  - Everything else identical to round 7 (passed, 176us).

#define T_LEN 256
#define I_SZ  32
#define H_SZ  64
#define O_SZ  8
#define BR    16
#define HS    72   // h row stride in shorts

typedef __attribute__((ext_vector_type(8))) short short8;
typedef __attribute__((ext_vector_type(4))) float f32x4;

static __device__ __forceinline__ unsigned fbits(float f) {
    union { float f; unsigned u; } v; v.f = f; return v.u;
}
// two floats -> packed bf16x2 (truncation): elem0 = lo, elem1 = hi
static __device__ __forceinline__ unsigned pk2t(float lo, float hi) {
    return __builtin_amdgcn_perm(fbits(hi), fbits(lo), 0x07060302u);
}
static __device__ __forceinline__ short f2bf_rne(float f) {   // init-time only
    union { __hip_bfloat16 b; short s; } u;
    u.b = __float2bfloat16(f);
    return u.s;
}
static __device__ __forceinline__ f32x4 rcp4(f32x4 d) {
    f32x4 r;
    r.x = __builtin_amdgcn_rcpf(d.x);
    r.y = __builtin_amdgcn_rcpf(d.y);
    r.z = __builtin_amdgcn_rcpf(d.z);
    r.w = __builtin_amdgcn_rcpf(d.w);
    return r;
}
static __device__ __forceinline__ f32x4 exp2_4(f32x4 m) {
    f32x4 e;
    e.x = __builtin_amdgcn_exp2f(m.x);
    e.y = __builtin_amdgcn_exp2f(m.y);
    e.z = __builtin_amdgcn_exp2f(m.z);
    e.w = __builtin_amdgcn_exp2f(m.w);
    return e;
}
static __device__ __forceinline__ f32x4 clamp4(f32x4 x, float lo, float hi) {
    f32x4 r;
    r.x = __builtin_amdgcn_fmed3f(x.x, lo, hi);
    r.y = __builtin_amdgcn_fmed3f(x.y, lo, hi);
    r.z = __builtin_amdgcn_fmed3f(x.z, lo, hi);
    r.w = __builtin_amdgcn_fmed3f(x.w, lo, hi);
    return r;
}
#define LOG2E     1.4426950408889634f
#define TWO_LOG2E 2.8853900817779268f

// sigmoid(x) = 1/(1+exp(-x)) = rcp(1 + exp2(-x*log2e)).
// Large |x| is graceful: exp2->inf => rcp->0; exp2->0 => rcp(1)=1.
static __device__ __forceinline__ f32x4 sig4(f32x4 x) {
    f32x4 e = exp2_4(x * (-LOG2E));
    return rcp4(e + 1.0f);
}
// tanh(x) = (e-1)/(e+1), e = exp2(2x*log2e). Clamp input so e stays finite.
static __device__ __forceinline__ f32x4 tanh4(f32x4 x) {
    f32x4 xc = clamp4(x, -10.0f, 10.0f);
    f32x4 e  = exp2_4(xc * TWO_LOG2E);
    return (e - 1.0f) * rcp4(e + 1.0f);
}

__global__ __launch_bounds__(256, 1)
void lstm_fused_kernel(const float* __restrict__ x,
                       const float* __restrict__ W_ih,
                       const float* __restrict__ W_hh,
                       const float* __restrict__ b_ih,
                       const float* __restrict__ b_hh,
                       const float* __restrict__ W_fc,
                       const float* __restrict__ b_fc,
                       float* __restrict__ out)
{
    __shared__ short hbuf[2][BR][HS];   // h double buffer, bf16, 16 real rows
    __shared__ float Hf[BR][64];

    const int tid   = threadIdx.x;
    const int wave  = tid >> 6;
    const int lane  = tid & 63;
    const int quad  = lane >> 4;
    const int nlow  = lane & 15;
    const int jw    = wave * 16 + nlow;  // hidden col this lane's tiles own
    const int rbase = quad * 4;          // D rows this lane owns (real rows)
    const int b0    = blockIdx.x * BR;

    // ---- B fragments (weights) once into registers: 4 gates x 3 k-tiles.
    short8 bfrag[4][3];
    f32x4  biasf[4];
    for (int g = 0; g < 4; ++g) {
        const int col = g * 64 + jw;
        {
            const float* wr = W_ih + col * I_SZ + quad * 8;
            short8 f;
            #pragma unroll
            for (int e = 0; e < 8; ++e) f[e] = f2bf_rne(wr[e]);
            bfrag[g][0] = f;
        }
        #pragma unroll
        for (int kt = 1; kt < 3; ++kt) {
            const float* wr = W_hh + col * H_SZ + (kt - 1) * 32 + quad * 8;
            short8 f;
            #pragma unroll
            for (int e = 0; e < 8; ++e) f[e] = f2bf_rne(wr[e]);
            bfrag[g][kt] = f;
        }
        const float bg = b_ih[col] + b_hh[col];
        biasf[g] = (f32x4){bg, bg, bg, bg};
    }

    // ---- zero h buffers (h0 = 0)
    for (int q = tid; q < 2 * BR * HS; q += 256) ((short*)hbuf)[q] = (short)0;

    // ---- x machinery: lane owns x[b0+nlow][t][quad*8 .. +7] (A row = nlow).
    const float* xb = x + ((size_t)(b0 + nlow) * T_LEN) * I_SZ + quad * 8;

    float4 nx[16];                        // next-chunk fp32 (8 steps x 8 floats)
    short8 sc[8];                         // current-chunk bf16 fragments
    #pragma unroll
    for (int s = 0; s < 8; ++s) {
        nx[2*s]   = *(const float4*)(xb + s * I_SZ);
        nx[2*s+1] = *(const float4*)(xb + s * I_SZ + 4);
    }
    #pragma unroll
    for (int s = 0; s < 8; ++s) {
        union { uint4 u; short8 v; } w;
        w.u.x = pk2t(nx[2*s].x,   nx[2*s].y);
        w.u.y = pk2t(nx[2*s].z,   nx[2*s].w);
        w.u.z = pk2t(nx[2*s+1].x, nx[2*s+1].y);
        w.u.w = pk2t(nx[2*s+1].z, nx[2*s+1].w);
        sc[s] = w.v;
    }

    // LDS addresses: read A rows by nlow; write own 4 cell rows at col jw.
    const short* rb[2] = { &hbuf[0][nlow][quad * 8], &hbuf[1][nlow][quad * 8] };
    short*       wb[2] = { &hbuf[0][rbase][jw],      &hbuf[1][rbase][jw] };

    f32x4 cc = {0.f, 0.f, 0.f, 0.f};
    f32x4 hh = {0.f, 0.f, 0.f, 0.f};

    for (int ch = 0; ch < 32; ++ch) {
        #pragma unroll
        for (int tc = 0; tc < 8; ++tc) {
            const int t = ch * 8 + tc;

            __syncthreads();             // h_{t-1} (and at t=0 the zeroing) visible

            // h fragments: A[m = nlow][k = 32*kt + quad*8 + e]
            const short* hr = rb[t & 1];
            short8 a1 = *(const short8*)(hr);        // h cols  0..31
            short8 a2 = *(const short8*)(hr + 32);   // h cols 32..63

            // issue next chunk's global loads early in the chunk
            if (tc == 0 && ch + 1 < 32) {
                const float* nxt = xb + (t + 8) * I_SZ;
                #pragma unroll
                for (int s = 0; s < 8; ++s) {
                    nx[2*s]   = *(const float4*)(nxt + s * I_SZ);
                    nx[2*s+1] = *(const float4*)(nxt + s * I_SZ + 4);
                }
            }

            const short8 ax = sc[tc];

            // 4 independent gate chains; x-proj MFMA issues in the lgkm shadow.
            f32x4 acc[4];
            #pragma unroll
            for (int g = 0; g < 4; ++g) {
                f32x4 a = __builtin_amdgcn_mfma_f32_16x16x32_bf16(ax, bfrag[g][0], biasf[g], 0, 0, 0);
                a = __builtin_amdgcn_mfma_f32_16x16x32_bf16(a1, bfrag[g][1], a, 0, 0, 0);
                a = __builtin_amdgcn_mfma_f32_16x16x32_bf16(a2, bfrag[g][2], a, 0, 0, 0);
                acc[g] = a;
            }

            // convert next chunk once its loads landed (7 steps of cover);
            // independent ops = ILP filler for the MFMA/activation chains.
            if (tc == 7 && ch + 1 < 32) {
                #pragma unroll
                for (int s = 0; s < 8; ++s) {
                    union { uint4 u; short8 v; } w;
                    w.u.x = pk2t(nx[2*s].x,   nx[2*s].y);
                    w.u.y = pk2t(nx[2*s].z,   nx[2*s].w);
                    w.u.z = pk2t(nx[2*s+1].x, nx[2*s+1].y);
                    w.u.w = pk2t(nx[2*s+1].z, nx[2*s+1].w);
                    sc[s] = w.v;
                }
            }

            // ---- cell update: 4 real cells per lane, trans-pipe activations.
            f32x4 iv = sig4(acc[0]);
            f32x4 fv = sig4(acc[1]);
            f32x4 gv = tanh4(acc[2]);
            f32x4 ov = sig4(acc[3]);
            cc = __builtin_elementwise_fma(fv, cc, iv * gv);
            hh = ov * tanh4(cc);

            // h store: truncation pack, 4x ds_write_b16
            short* hw = wb[(t + 1) & 1];
            hw[0 * HS] = (short)((fbits(hh.x) + 0x8000u) >> 16);
            hw[1 * HS] = (short)((fbits(hh.y) + 0x8000u) >> 16);
            hw[2 * HS] = (short)((fbits(hh.z) + 0x8000u) >> 16);
            hw[3 * HS] = (short)((fbits(hh.w) + 0x8000u) >> 16);
        }
    }

    // ---- epilogue: out[b0+r][o] = h_T[r] . W_fc[o] + b_fc[o]  (fp32 h)
    Hf[rbase + 0][jw] = hh.x;
    Hf[rbase + 1][jw] = hh.y;
    Hf[rbase + 2][jw] = hh.z;
    Hf[rbase + 3][jw] = hh.w;
    __syncthreads();

    if (tid < BR * O_SZ) {               // 128 threads
        const int r = tid >> 3;
        const int o = tid & 7;
        const float* wf = W_fc + o * H_SZ;
        float acc = b_fc[o];
        #pragma unroll
        for (int jx = 0; jx < H_SZ; ++jx) acc += Hf[r][jx] * wf[jx];
        out[(size_t)(b0 + r) * O_SZ + o] = acc;
    }
}

extern "C" void kernel_launch(void* const* d_in, const int* in_sizes, int n_in,
                              void* d_out, int out_size, void* d_ws, size_t ws_size,
                              hipStream_t stream) {
    const float* x    = (const float*)d_in[0];
    const float* W_ih = (const float*)d_in[1];
    const float* W_hh = (const float*)d_in[2];
    const float* b_ih = (const float*)d_in[3];
    const float* b_hh = (const float*)d_in[4];
    const float* W_fc = (const float*)d_in[5];
    const float* b_fc = (const float*)d_in[6];
    float* out = (float*)d_out;

    const int B = 4096;
    lstm_fused_kernel<<<dim3(B / BR), dim3(256), 0, stream>>>(
        x, W_ih, W_hh, b_ih, b_hh, W_fc, b_fc, out);
}